// Round 23
// baseline (119.152 us; speedup 1.0000x reference)
//
#include <hip/hip_runtime.h>
#include <math.h>

namespace {

constexpr int NB = 4, NS = 2048, ND = 256, NH = 4, NDK = 64, NL = 2, NT = 1000;
constexpr float L2E = 1.44269504089f;       // log2(e)
constexpr float QSCALE = 0.125f * L2E;      // 1/sqrt(DK) * log2(e), folded into Wq/bq

typedef short bfx8 __attribute__((ext_vector_type(8)));
typedef float f32x4 __attribute__((ext_vector_type(4)));
typedef float f32x16 __attribute__((ext_vector_type(16)));

static __device__ __forceinline__ short f2bf(float f) {
  union { float f; unsigned u; } v; v.f = f;
  unsigned u = v.u;
  unsigned r = (u + 0x7fffu + ((u >> 16) & 1u)) >> 16;   // RNE
  return (short)r;
}
static __device__ __forceinline__ float bf2f(short s) {
  union { float f; unsigned u; } v; v.u = ((unsigned)(unsigned short)s) << 16;
  return v.f;
}
static __device__ __forceinline__ float exp2_hw(float x) {
  float r;
  asm("v_exp_f32 %0, %1" : "=v"(r) : "v"(x));
  return r;
}
static __device__ __forceinline__ unsigned cvt_pk_bf16(float lo, float hi) {
  unsigned d;
  asm("v_cvt_pk_bf16_f32 %0, %1, %2" : "=v"(d) : "v"(lo), "v"(hi));
  return d;
}

// ------- fused weight-pack + embedding + sbias (one launch) ------------------
// blocks [0,128): packw; [128,2176): embed (4 rows each); [2176,2432): sbias
// for BOTH layers: sbias_g[(l*16+bh)*NS+key] = mask ? tp_l[td]*L2E : -1e9.
__global__ __launch_bounds__(256) void k_packem(const int* __restrict__ x,
                                                const int* __restrict__ td,
                                                const int* __restrict__ mask,
                                                const float* __restrict__ tp,
                                                const float* __restrict__ ee,
                                                const float* __restrict__ te,
                                                short* __restrict__ hb,
                                                const float* __restrict__ Wq,
                                                const float* __restrict__ Wk,
                                                const float* __restrict__ Wv,
                                                const float* __restrict__ Wo,
                                                const float* __restrict__ bq,
                                                const float* __restrict__ bk,
                                                const float* __restrict__ bv,
                                                short* __restrict__ wqkvT,
                                                short* __restrict__ woT,
                                                float* __restrict__ bqkv,
                                                float* __restrict__ sbias_g) {
  if (blockIdx.x < 128) {
    __shared__ float t[64][65];
    int bi = blockIdx.x;
    int z = bi >> 4, l = z >> 2, mat = z & 3;
    const float* src;
    short* dst;
    float scale = 1.f;
    if (mat == 0)      { src = Wq + (size_t)l * 65536; dst = wqkvT + (size_t)l * 768 * 256; scale = QSCALE; }
    else if (mat == 1) { src = Wk + (size_t)l * 65536; dst = wqkvT + (size_t)l * 768 * 256 + 256 * 256; }
    else if (mat == 2) { src = Wv + (size_t)l * 65536; dst = wqkvT + (size_t)l * 768 * 256 + 512 * 256; }
    else               { src = Wo + (size_t)l * 65536; dst = woT + (size_t)l * 65536; }
    int k0 = (bi & 3) * 64, n0 = ((bi >> 2) & 3) * 64;
    int c = threadIdx.x & 63, r4 = threadIdx.x >> 6;
    #pragma unroll
    for (int rr = 0; rr < 64; rr += 4) t[rr + r4][c] = src[(size_t)(k0 + rr + r4) * 256 + n0 + c];
    __syncthreads();
    #pragma unroll
    for (int rr = 0; rr < 64; rr += 4) {
      int n = rr + r4;
      dst[(size_t)(n0 + n) * 256 + k0 + c] = f2bf(t[c][n] * scale);
    }
    if (mat == 0 && (bi & 15) == 0) {
      for (int cc = threadIdx.x; cc < 768; cc += 256) {
        float v = cc < 256 ? bq[l * 256 + cc] * QSCALE
                           : (cc < 512 ? bk[l * 256 + cc - 256] : bv[l * 256 + cc - 512]);
        bqkv[l * 768 + cc] = v;
      }
    }
  } else if (blockIdx.x < 128 + 2048) {
    int lane = threadIdx.x & 63, r4 = threadIdx.x >> 6;
    int row = (blockIdx.x - 128) * 4 + r4;
    int xi = x[row];
    int tb = td[row];
    tb = tb < 0 ? 0 : (tb >= NT ? NT - 1 : tb);
    float4 e = ((const float4*)&ee[(size_t)xi * ND])[lane];
    float4 tv = ((const float4*)&te[(size_t)tb * ND])[lane];
    short4 ob;
    ob.x = f2bf(e.x + tv.x); ob.y = f2bf(e.y + tv.y);
    ob.z = f2bf(e.z + tv.z); ob.w = f2bf(e.w + tv.w);
    ((short4*)&hb[(size_t)row * ND])[lane] = ob;
  } else {
    int flat = (blockIdx.x - 2176) * 256 + threadIdx.x;   // 0 .. 65535
    int l = flat >> 15;
    int rem = flat & 32767;
    int bh = rem >> 11, key = rem & 2047;
    int b = bh >> 2, hh = bh & 3;
    int tb = td[b * NS + key];
    tb = tb < 0 ? 0 : (tb >= NT ? NT - 1 : tb);
    float v = mask[b * NS + key] ? tp[(size_t)l * NT * NH + tb * NH + hh] * L2E : -1e9f;
    sbias_g[(size_t)(l * 16 + bh) * NS + key] = v;
  }
}

// ---------------- MFMA GEMM: 64x128 tile, BK=64, K=256 -----------------------
template <int OUT_BF16>
__global__ __launch_bounds__(256) void k_gemm(const short* __restrict__ A,
                                              const short* __restrict__ BT,
                                              const float* __restrict__ bias,
                                              void* __restrict__ C, int ldc,
                                              int mb_mul, int mb_add, int n_base) {
  constexpr int LP = 76;
  __shared__ short at[64][LP];
  __shared__ short bt[128][LP];
  int tid = threadIdx.x;
  int w = tid >> 6, lane = tid & 63, ln15 = lane & 15, g = lane >> 4;
  int m0 = (blockIdx.x * mb_mul + mb_add) * 64;
  int n0 = n_base + blockIdx.y * 128;
  int srow = tid >> 2, scol = (tid & 3) * 16;
  int brow = tid >> 1, bcol = (tid & 1) * 32;

  f32x4 acc[8];
  #pragma unroll
  for (int nt = 0; nt < 8; ++nt) acc[nt] = (f32x4){0.f, 0.f, 0.f, 0.f};

  bfx8 a0, a1, b0, b1, b2, b3;
  auto LOAD = [&](int kk0) {
    const short* as = &A[(size_t)(m0 + srow) * 256 + kk0 + scol];
    a0 = *(const bfx8*)as; a1 = *(const bfx8*)(as + 8);
    const short* bs = &BT[(size_t)(n0 + brow) * 256 + kk0 + bcol];
    b0 = *(const bfx8*)bs; b1 = *(const bfx8*)(bs + 8);
    b2 = *(const bfx8*)(bs + 16); b3 = *(const bfx8*)(bs + 24);
  };
  LOAD(0);
  for (int kk0 = 0; kk0 < 256; kk0 += 64) {
    __syncthreads();
    *(bfx8*)&at[srow][scol] = a0; *(bfx8*)&at[srow][scol + 8] = a1;
    *(bfx8*)&bt[brow][bcol] = b0; *(bfx8*)&bt[brow][bcol + 8] = b1;
    *(bfx8*)&bt[brow][bcol + 16] = b2; *(bfx8*)&bt[brow][bcol + 24] = b3;
    __syncthreads();
    if (kk0 + 64 < 256) LOAD(kk0 + 64);
    #pragma unroll
    for (int ks = 0; ks < 2; ++ks) {
      bfx8 af = *(const bfx8*)&at[w * 16 + ln15][ks * 32 + g * 8];
      #pragma unroll
      for (int nt = 0; nt < 8; ++nt) {
        bfx8 bf = *(const bfx8*)&bt[nt * 16 + ln15][ks * 32 + g * 8];
        acc[nt] = __builtin_amdgcn_mfma_f32_16x16x32_bf16(af, bf, acc[nt], 0, 0, 0);
      }
    }
  }

  #pragma unroll
  for (int nt = 0; nt < 8; ++nt) {
    int col = n0 + nt * 16 + ln15;
    float bb = bias[col];
    #pragma unroll
    for (int r = 0; r < 4; ++r) {
      int row = m0 + w * 16 + g * 4 + r;
      float val = acc[nt][r] + bb;
      if (OUT_BF16) ((short*)C)[(size_t)row * ldc + col] = f2bf(val);
      else          ((float*)C)[(size_t)row * ldc + col] = val;
    }
  }
}

// ---------------- V-projection GEMM: writes vT directly transposed -----------
// Same body as k_gemm; epilogue stores V[b, s, col] at vT[((b*NH+hh)*32+tile)
// *64+dim][key] (short4 per nt, key-stride-1). Replaces qkv-V write + k_frag.
__global__ __launch_bounds__(256) void k_gemmv(const short* __restrict__ A,
                                               const short* __restrict__ BT,
                                               const float* __restrict__ bias,
                                               short* __restrict__ vT,
                                               int mb_mul, int mb_add) {
  constexpr int LP = 76;
  __shared__ short at[64][LP];
  __shared__ short bt[128][LP];
  int tid = threadIdx.x;
  int w = tid >> 6, lane = tid & 63, ln15 = lane & 15, g = lane >> 4;
  int m0 = (blockIdx.x * mb_mul + mb_add) * 64;
  int n0 = blockIdx.y * 128;
  int srow = tid >> 2, scol = (tid & 3) * 16;
  int brow = tid >> 1, bcol = (tid & 1) * 32;

  f32x4 acc[8];
  #pragma unroll
  for (int nt = 0; nt < 8; ++nt) acc[nt] = (f32x4){0.f, 0.f, 0.f, 0.f};

  bfx8 a0, a1, b0, b1, b2, b3;
  auto LOAD = [&](int kk0) {
    const short* as = &A[(size_t)(m0 + srow) * 256 + kk0 + scol];
    a0 = *(const bfx8*)as; a1 = *(const bfx8*)(as + 8);
    const short* bs = &BT[(size_t)(n0 + brow) * 256 + kk0 + bcol];
    b0 = *(const bfx8*)bs; b1 = *(const bfx8*)(bs + 8);
    b2 = *(const bfx8*)(bs + 16); b3 = *(const bfx8*)(bs + 24);
  };
  LOAD(0);
  for (int kk0 = 0; kk0 < 256; kk0 += 64) {
    __syncthreads();
    *(bfx8*)&at[srow][scol] = a0; *(bfx8*)&at[srow][scol + 8] = a1;
    *(bfx8*)&bt[brow][bcol] = b0; *(bfx8*)&bt[brow][bcol + 8] = b1;
    *(bfx8*)&bt[brow][bcol + 16] = b2; *(bfx8*)&bt[brow][bcol + 24] = b3;
    __syncthreads();
    if (kk0 + 64 < 256) LOAD(kk0 + 64);
    #pragma unroll
    for (int ks = 0; ks < 2; ++ks) {
      bfx8 af = *(const bfx8*)&at[w * 16 + ln15][ks * 32 + g * 8];
      #pragma unroll
      for (int nt = 0; nt < 8; ++nt) {
        bfx8 bf = *(const bfx8*)&bt[nt * 16 + ln15][ks * 32 + g * 8];
        acc[nt] = __builtin_amdgcn_mfma_f32_16x16x32_bf16(af, bf, acc[nt], 0, 0, 0);
      }
    }
  }

  int b = m0 >> 11, s0 = m0 & 2047;
  int tile = s0 >> 6, key0 = w * 16 + g * 4;
  #pragma unroll
  for (int nt = 0; nt < 8; ++nt) {
    int col = n0 + nt * 16 + ln15;      // 0..255 in V space
    int hh = col >> 6, dim = col & 63;
    float bb = bias[col];
    short4 ov;
    ov.x = f2bf(acc[nt][0] + bb);
    ov.y = f2bf(acc[nt][1] + bb);
    ov.z = f2bf(acc[nt][2] + bb);
    ov.w = f2bf(acc[nt][3] + bb);
    *(short4*)&vT[(((size_t)(b * NH + hh) * 32 + tile) * 64 + dim) * 64 + key0] = ov;
  }
}

// ---------------- fused merge+proj, layer 0 (NC=2, bf16 out) -----------------
__global__ __launch_bounds__(256) void k_pmerge(const short* __restrict__ partO,
                                                const float* __restrict__ partML,
                                                const short* __restrict__ BT,
                                                const float* __restrict__ bias,
                                                short* __restrict__ C) {
  constexpr int LP = 76;
  constexpr int NC = 2;
  __shared__ short at[64][LP];
  __shared__ short bt[128][LP];
  int tid = threadIdx.x;
  int w = tid >> 6, lane = tid & 63, ln15 = lane & 15, g = lane >> 4;
  int m0 = blockIdx.x * 64;
  int n0 = blockIdx.y * 128;
  int srow = tid >> 2, scol = (tid & 3) * 16;
  int brow = tid >> 1, bcol = (tid & 1) * 32;

  int grow = m0 + srow;
  int b = grow >> 11, s = grow & 2047;     // NS = 2048

  f32x4 acc[8];
  #pragma unroll
  for (int nt = 0; nt < 8; ++nt) acc[nt] = (f32x4){0.f, 0.f, 0.f, 0.f};

  bfx8 a0, a1, b0_, b1_, b2_, b3_;
  auto LOAD = [&](int kk0) {
    int hh2 = kk0 >> 6;
    size_t rbase = (size_t)(b * NH + hh2) * NS + s;
    float2 ml[NC];
    float M = -1e30f;
    #pragma unroll
    for (int c = 0; c < NC; ++c) {
      ml[c] = *(const float2*)&partML[(rbase + (size_t)c * 16 * NS) * 2];
      M = fmaxf(M, ml[c].x);
    }
    float wgt[NC], L = 0.f;
    #pragma unroll
    for (int c = 0; c < NC; ++c) { wgt[c] = exp2_hw(ml[c].x - M); L += ml[c].y * wgt[c]; }
    float inv = 1.f / L;
    float av[16];
    #pragma unroll
    for (int i = 0; i < 16; ++i) av[i] = 0.f;
    #pragma unroll
    for (int c = 0; c < NC; ++c) {
      float wc = wgt[c] * inv;
      size_t row = rbase + (size_t)c * 16 * NS;
      union { int4 v; short sh[8]; } ua, ub;
      ua.v = *(const int4*)&partO[row * 64 + scol];
      ub.v = *(const int4*)&partO[row * 64 + scol + 8];
      #pragma unroll
      for (int i = 0; i < 8; ++i) {
        av[i]     = fmaf(bf2f(ua.sh[i]), wc, av[i]);
        av[8 + i] = fmaf(bf2f(ub.sh[i]), wc, av[8 + i]);
      }
    }
    union { bfx8 v; short sh[8]; } pa, pb;
    #pragma unroll
    for (int i = 0; i < 8; ++i) { pa.sh[i] = f2bf(av[i]); pb.sh[i] = f2bf(av[8 + i]); }
    a0 = pa.v; a1 = pb.v;
    const short* bs = &BT[(size_t)(n0 + brow) * 256 + kk0 + bcol];
    b0_ = *(const bfx8*)bs; b1_ = *(const bfx8*)(bs + 8);
    b2_ = *(const bfx8*)(bs + 16); b3_ = *(const bfx8*)(bs + 24);
  };
  LOAD(0);
  for (int kk0 = 0; kk0 < 256; kk0 += 64) {
    __syncthreads();
    *(bfx8*)&at[srow][scol] = a0; *(bfx8*)&at[srow][scol + 8] = a1;
    *(bfx8*)&bt[brow][bcol] = b0_; *(bfx8*)&bt[brow][bcol + 8] = b1_;
    *(bfx8*)&bt[brow][bcol + 16] = b2_; *(bfx8*)&bt[brow][bcol + 24] = b3_;
    __syncthreads();
    if (kk0 + 64 < 256) LOAD(kk0 + 64);
    #pragma unroll
    for (int ks = 0; ks < 2; ++ks) {
      bfx8 af = *(const bfx8*)&at[w * 16 + ln15][ks * 32 + g * 8];
      #pragma unroll
      for (int nt = 0; nt < 8; ++nt) {
        bfx8 bf = *(const bfx8*)&bt[nt * 16 + ln15][ks * 32 + g * 8];
        acc[nt] = __builtin_amdgcn_mfma_f32_16x16x32_bf16(af, bf, acc[nt], 0, 0, 0);
      }
    }
  }

  #pragma unroll
  for (int nt = 0; nt < 8; ++nt) {
    int col = n0 + nt * 16 + ln15;
    float bb = bias[col];
    #pragma unroll
    for (int r = 0; r < 4; ++r) {
      int row = m0 + w * 16 + g * 4 + r;
      C[(size_t)row * 256 + col] = f2bf(acc[nt][r] + bb);
    }
  }
}

// ---------------- fused merge+proj, layer-1 tail (NC=16, fp32 out) -----------
__global__ __launch_bounds__(256) void k_gmerge(const short* __restrict__ partO,
                                                const float* __restrict__ partML,
                                                const short* __restrict__ BT,
                                                const float* __restrict__ bias,
                                                float* __restrict__ C) {
  constexpr int LP = 76;
  constexpr int NC = 16;
  __shared__ short at[64][LP];
  __shared__ short bt[128][LP];
  int tid = threadIdx.x;
  int w = tid >> 6, lane = tid & 63, ln15 = lane & 15, g = lane >> 4;
  int m0 = (blockIdx.x * 32 + 31) * 64;    // last 64 rows of batch blockIdx.x
  int n0 = blockIdx.y * 128;
  int srow = tid >> 2, scol = (tid & 3) * 16;
  int brow = tid >> 1, bcol = (tid & 1) * 32;

  int grow = m0 + srow;
  int b = grow >> 11, s = grow & 2047;
  int qloc = s - (NS - 128);               // 64..127 within the 128-q partial block

  f32x4 acc[8];
  #pragma unroll
  for (int nt = 0; nt < 8; ++nt) acc[nt] = (f32x4){0.f, 0.f, 0.f, 0.f};

  bfx8 a0, a1, b0_, b1_, b2_, b3_;
  auto LOAD = [&](int kk0) {
    int hh2 = kk0 >> 6;
    size_t rbase = (size_t)(b * NH + hh2) * 128 + qloc;
    float M = -1e30f;
    float mls[NC], lls[NC];
    #pragma unroll
    for (int c = 0; c < NC; ++c) {
      float2 ml = *(const float2*)&partML[(rbase + (size_t)c * 16 * 128) * 2];
      mls[c] = ml.x; lls[c] = ml.y;
      M = fmaxf(M, ml.x);
    }
    float L = 0.f, wgt[NC];
    #pragma unroll
    for (int c = 0; c < NC; ++c) { wgt[c] = exp2_hw(mls[c] - M); L += lls[c] * wgt[c]; }
    float inv = 1.f / L;
    float av[16];
    #pragma unroll
    for (int i = 0; i < 16; ++i) av[i] = 0.f;
    #pragma unroll
    for (int c = 0; c < NC; ++c) {
      float wc = wgt[c] * inv;
      size_t row = rbase + (size_t)c * 16 * 128;
      union { int4 v; short sh[8]; } ua, ub;
      ua.v = *(const int4*)&partO[row * 64 + scol];
      ub.v = *(const int4*)&partO[row * 64 + scol + 8];
      #pragma unroll
      for (int i = 0; i < 8; ++i) {
        av[i]     = fmaf(bf2f(ua.sh[i]), wc, av[i]);
        av[8 + i] = fmaf(bf2f(ub.sh[i]), wc, av[8 + i]);
      }
    }
    union { bfx8 v; short sh[8]; } pa, pb;
    #pragma unroll
    for (int i = 0; i < 8; ++i) { pa.sh[i] = f2bf(av[i]); pb.sh[i] = f2bf(av[8 + i]); }
    a0 = pa.v; a1 = pb.v;
    const short* bs = &BT[(size_t)(n0 + brow) * 256 + kk0 + bcol];
    b0_ = *(const bfx8*)bs; b1_ = *(const bfx8*)(bs + 8);
    b2_ = *(const bfx8*)(bs + 16); b3_ = *(const bfx8*)(bs + 24);
  };
  LOAD(0);
  for (int kk0 = 0; kk0 < 256; kk0 += 64) {
    __syncthreads();
    *(bfx8*)&at[srow][scol] = a0; *(bfx8*)&at[srow][scol + 8] = a1;
    *(bfx8*)&bt[brow][bcol] = b0_; *(bfx8*)&bt[brow][bcol + 8] = b1_;
    *(bfx8*)&bt[brow][bcol + 16] = b2_; *(bfx8*)&bt[brow][bcol + 24] = b3_;
    __syncthreads();
    if (kk0 + 64 < 256) LOAD(kk0 + 64);
    #pragma unroll
    for (int ks = 0; ks < 2; ++ks) {
      bfx8 af = *(const bfx8*)&at[w * 16 + ln15][ks * 32 + g * 8];
      #pragma unroll
      for (int nt = 0; nt < 8; ++nt) {
        bfx8 bf = *(const bfx8*)&bt[nt * 16 + ln15][ks * 32 + g * 8];
        acc[nt] = __builtin_amdgcn_mfma_f32_16x16x32_bf16(af, bf, acc[nt], 0, 0, 0);
      }
    }
  }

  #pragma unroll
  for (int nt = 0; nt < 8; ++nt) {
    int col = n0 + nt * 16 + ln15;
    float bb = bias[col];
    #pragma unroll
    for (int r = 0; r < 4; ++r) {
      int row = m0 + w * 16 + g * 4 + r;
      C[(size_t)row * 256 + col] = acc[nt][r] + bb;
    }
  }
}

// ---------------- MFMA flash attention: 32x32x16 fragments (R20 proven) ------
__global__ __launch_bounds__(256) void k_attn(const short* __restrict__ qkv,
                                              const short* __restrict__ vT,
                                              const float* __restrict__ sbias_g,
                                              short* __restrict__ partO,
                                              float* __restrict__ partML,
                                              int q_base, int qcount, int nchunk) {
  constexpr int LP = 76;
  __shared__ short kt[64][LP];   // K tile [key][dim]
  __shared__ short vt[64][LP];   // V^T tile [dim][key]
  __shared__ float sbias[64];

  int tid = threadIdx.x;
  int w = tid >> 6, lane = tid & 63, q31 = lane & 31, hl = lane >> 5;
  int b = blockIdx.z, hh = blockIdx.y;
  int bh = b * NH + hh;
  int qtile = blockIdx.x / nchunk;
  int chunk = blockIdx.x - qtile * nchunk;
  int niter = NS / (64 * nchunk);
  int tbase = chunk * niter;
  int q0 = q_base + qtile * 128;
  int qq = q0 + w * 32 + q31;      // this lane's query row

  bfx8 aq[4];
  #pragma unroll
  for (int ki = 0; ki < 4; ++ki)
    aq[ki] = *(const bfx8*)&qkv[(size_t)(b * NS + qq) * 768 + hh * NDK + ki * 16 + hl * 8];

  f32x16 o[2];
  #pragma unroll
  for (int dt = 0; dt < 2; ++dt)
    #pragma unroll
    for (int i = 0; i < 16; ++i) o[dt][i] = 0.f;
  float m = -1e30f, lsum = 0.f;

  int srow = tid >> 2, scg = (tid & 3) * 16;

  bfx8 kr0, kr1, vr0, vr1;
  float br = 0.f;
  auto loadset = [&](int it) {
    int tt = tbase + it;
    int k0 = tt * 64;
    const short* ksrc = &qkv[(size_t)(b * NS + k0 + srow) * 768 + 256 + hh * NDK + scg];
    kr0 = *(const bfx8*)ksrc; kr1 = *(const bfx8*)(ksrc + 8);
    const short* vsrc = &vT[(((size_t)bh * 32 + tt) * 64 + srow) * 64 + scg];
    vr0 = *(const bfx8*)vsrc; vr1 = *(const bfx8*)(vsrc + 8);
    if (tid < 64) br = sbias_g[(size_t)bh * NS + k0 + tid];
  };

  loadset(0);
  for (int it = 0; it < niter; ++it) {
    __syncthreads();
    *(bfx8*)&kt[srow][scg] = kr0;
    *(bfx8*)&kt[srow][scg + 8] = kr1;
    *(bfx8*)&vt[srow][scg] = vr0;
    *(bfx8*)&vt[srow][scg + 8] = vr1;
    if (tid < 64) sbias[tid] = br;
    __syncthreads();
    if (it + 1 < niter) loadset(it + 1);

    f32x16 c[2];
    #pragma unroll
    for (int kt2 = 0; kt2 < 2; ++kt2)
      #pragma unroll
      for (int i = 0; i < 16; ++i) c[kt2][i] = 0.f;
    __builtin_amdgcn_s_setprio(1);
    #pragma unroll
    for (int kt2 = 0; kt2 < 2; ++kt2) {
      #pragma unroll
      for (int ki = 0; ki < 4; ++ki) {
        bfx8 kf = *(const bfx8*)&kt[kt2 * 32 + q31][ki * 16 + hl * 8];
        c[kt2] = __builtin_amdgcn_mfma_f32_32x32x16_bf16(kf, aq[ki], c[kt2], 0, 0, 0);
      }
    }
    __builtin_amdgcn_s_setprio(0);

    #pragma unroll
    for (int kt2 = 0; kt2 < 2; ++kt2) {
      #pragma unroll
      for (int rg = 0; rg < 4; ++rg) {
        float4 bb = *(const float4*)&sbias[kt2 * 32 + rg * 8 + hl * 4];
        c[kt2][rg * 4 + 0] += bb.x; c[kt2][rg * 4 + 1] += bb.y;
        c[kt2][rg * 4 + 2] += bb.z; c[kt2][rg * 4 + 3] += bb.w;
      }
    }
    float rm = c[0][0];
    #pragma unroll
    for (int kt2 = 0; kt2 < 2; ++kt2)
      #pragma unroll
      for (int i = 0; i < 16; ++i) rm = fmaxf(rm, c[kt2][i]);
    rm = fmaxf(rm, __shfl_xor(rm, 32, 64));
    if (__any(rm > m + 10.f)) {
      float nm = fmaxf(m, rm);
      float scl = exp2_hw(m - nm);
      m = nm;
      lsum *= scl;
      #pragma unroll
      for (int dt = 0; dt < 2; ++dt)
        #pragma unroll
        for (int i = 0; i < 16; ++i) o[dt][i] *= scl;
    }
    float ts = 0.f;
    #pragma unroll
    for (int kt2 = 0; kt2 < 2; ++kt2)
      #pragma unroll
      for (int i = 0; i < 16; ++i) { c[kt2][i] = exp2_hw(c[kt2][i] - m); ts += c[kt2][i]; }
    lsum += ts;

    __builtin_amdgcn_s_setprio(1);
    #pragma unroll
    for (int kt2 = 0; kt2 < 2; ++kt2) {
      #pragma unroll
      for (int ks = 0; ks < 2; ++ks) {
        unsigned pa0 = cvt_pk_bf16(c[kt2][8 * ks + 0], c[kt2][8 * ks + 1]);
        unsigned pa1 = cvt_pk_bf16(c[kt2][8 * ks + 2], c[kt2][8 * ks + 3]);
        unsigned pb0 = cvt_pk_bf16(c[kt2][8 * ks + 4], c[kt2][8 * ks + 5]);
        unsigned pb1 = cvt_pk_bf16(c[kt2][8 * ks + 6], c[kt2][8 * ks + 7]);
        asm volatile("v_permlane32_swap_b32 %0, %1" : "+v"(pa0), "+v"(pb0));
        asm volatile("v_permlane32_swap_b32 %0, %1" : "+v"(pa1), "+v"(pb1));
        union { unsigned u[4]; bfx8 v; } pf;
        pf.u[0] = pa0; pf.u[1] = pa1; pf.u[2] = pb0; pf.u[3] = pb1;
        #pragma unroll
        for (int dt = 0; dt < 2; ++dt) {
          bfx8 vf = *(const bfx8*)&vt[dt * 32 + q31][kt2 * 32 + ks * 16 + hl * 8];
          o[dt] = __builtin_amdgcn_mfma_f32_32x32x16_bf16(vf, pf.v, o[dt], 0, 0, 0);
        }
      }
    }
    __builtin_amdgcn_s_setprio(0);
  }

  lsum += __shfl_xor(lsum, 32, 64);

  size_t rowi = (size_t)(chunk * 16 + bh) * qcount + qtile * 128 + w * 32 + q31;
  #pragma unroll
  for (int dt = 0; dt < 2; ++dt) {
    #pragma unroll
    for (int rg = 0; rg < 4; ++rg) {
      int2 pk;
      pk.x = (int)cvt_pk_bf16(o[dt][rg * 4 + 0], o[dt][rg * 4 + 1]);
      pk.y = (int)cvt_pk_bf16(o[dt][rg * 4 + 2], o[dt][rg * 4 + 3]);
      *(int2*)&partO[rowi * 64 + dt * 32 + rg * 8 + hl * 4] = pk;
    }
  }
  if (hl == 0) { partML[rowi * 2] = m; partML[rowi * 2 + 1] = lsum; }
}

// ---------------- layernorm bf16->bf16 (layer 0, full rows) ------------------
__global__ __launch_bounds__(256) void k_lnb(const short* __restrict__ in,
                                             short* __restrict__ hb,
                                             const float* __restrict__ g_,
                                             const float* __restrict__ b_) {
  int lane = threadIdx.x & 63, r4 = threadIdx.x >> 6;
  size_t row = (size_t)blockIdx.y * NS + blockIdx.x * 4 + r4;
  short4 sv = ((const short4*)&in[row * ND])[lane];
  float vx = bf2f(sv.x), vy = bf2f(sv.y), vz = bf2f(sv.z), vw = bf2f(sv.w);
  float s = vx + vy + vz + vw;
  #pragma unroll
  for (int off = 1; off < 64; off <<= 1) s += __shfl_xor(s, off, 64);
  float mu = s * (1.f / ND);
  float dx = vx - mu, dy = vy - mu, dz = vz - mu, dw = vw - mu;
  float q = dx * dx + dy * dy + dz * dz + dw * dw;
  #pragma unroll
  for (int off = 1; off < 64; off <<= 1) q += __shfl_xor(q, off, 64);
  float rr = rsqrtf(q * (1.f / ND) + 1e-5f);
  float4 gg = ((const float4*)g_)[lane];
  float4 bb = ((const float4*)b_)[lane];
  short4 ob;
  ob.x = f2bf(dx * rr * gg.x + bb.x);
  ob.y = f2bf(dy * rr * gg.y + bb.y);
  ob.z = f2bf(dz * rr * gg.z + bb.z);
  ob.w = f2bf(dw * rr * gg.w + bb.w);
  ((short4*)&hb[row * ND])[lane] = ob;
}

// ---------------- fused tail LN (row NS-1 only) + classifier head ------------
__global__ __launch_bounds__(256) void k_lnhead(const float* __restrict__ h,
                                                const float* __restrict__ g_,
                                                const float* __restrict__ b_,
                                                const float* __restrict__ Wc1,
                                                const float* __restrict__ bc1,
                                                const float* __restrict__ Wc2,
                                                const float* __restrict__ bc2,
                                                float* __restrict__ out) {
  __shared__ float rowv[256];
  __shared__ float red[256];
  int b = blockIdx.x, j = threadIdx.x;
  float v = h[(size_t)(b * NS + NS - 1) * ND + j];
  red[j] = v;
  __syncthreads();
  for (int off = 128; off > 0; off >>= 1) {
    if (j < off) red[j] += red[j + off];
    __syncthreads();
  }
  float mu = red[0] * (1.f / ND);
  __syncthreads();
  float d = v - mu;
  red[j] = d * d;
  __syncthreads();
  for (int off = 128; off > 0; off >>= 1) {
    if (j < off) red[j] += red[j + off];
    __syncthreads();
  }
  float rr = rsqrtf(red[0] * (1.f / ND) + 1e-5f);
  rowv[j] = d * rr * g_[j] + b_[j];
  __syncthreads();
  float hid = 0.f;
  if (j < 128) {
    hid = bc1[j];
    for (int dd = 0; dd < ND; ++dd) hid = fmaf(rowv[dd], Wc1[dd * 128 + j], hid);
    hid = fmaxf(hid, 0.f) * Wc2[j];
  }
  __syncthreads();
  red[j] = j < 128 ? hid : 0.f;
  __syncthreads();
  for (int off = 64; off > 0; off >>= 1) {
    if (j < off) red[j] += red[j + off];
    __syncthreads();
  }
  if (j == 0) out[b] = 1.f / (1.f + __expf(-(red[0] + bc2[0])));
}

}  // namespace

extern "C" void kernel_launch(void* const* d_in, const int* in_sizes, int n_in,
                              void* d_out, int out_size, void* d_ws, size_t ws_size,
                              hipStream_t stream) {
  const int* x = (const int*)d_in[0];
  const int* td = (const int*)d_in[1];
  const int* mask = (const int*)d_in[2];
  const float* ee = (const float*)d_in[3];
  const float* te = (const float*)d_in[4];
  const float* Wq = (const float*)d_in[5];
  const float* bq = (const float*)d_in[6];
  const float* Wk = (const float*)d_in[7];
  const float* bk = (const float*)d_in[8];
  const float* Wv = (const float*)d_in[9];
  const float* bv = (const float*)d_in[10];
  const float* tp = (const float*)d_in[11];
  const float* Wo = (const float*)d_in[12];
  const float* bo = (const float*)d_in[13];
  const float* lng = (const float*)d_in[14];
  const float* lnb = (const float*)d_in[15];
  const float* Wc1 = (const float*)d_in[16];
  const float* bc1 = (const float*)d_in[17];
  const float* Wc2 = (const float*)d_in[18];
  const float* bc2 = (const float*)d_in[19];
  float* out = (float*)d_out;

  char* ws = (char*)d_ws;
  const size_t M = (size_t)NB * NS;  // 8192
  // Disjoint layout (verified R17/R20-R22); sbias_g now 256 KB (both layers)
  short* qkv     = (short*)(ws);                            // 0    .. 12 MB
  float* h       = (float*)(ws + (12 << 20));               // 12   .. 20 MB (L1 tail rows)
  short* hb      = (short*)(ws + (20 << 20));               // 20   .. 24 MB
  short* vT      = (short*)(ws + (24 << 20));               // 24   .. 28 MB
  short* wqkvT   = (short*)(ws + (28 << 20) + (128 << 10)); // 28.125 .. 28.875 MB
  short* woT     = (short*)(ws + (28 << 20) + (896 << 10)); // 28.875 .. 29.125 MB
  float* bqkv    = (float*)(ws + (28 << 20) + (1152 << 10)); // 29.125 .. 29.133 MB
  short* partO   = (short*)(ws + (30 << 20));               // 30   .. 46.8 MB
  float* partML  = (float*)(ws + (47 << 20));               // 47   .. 48 MB
  short* hraw    = (short*)(ws + (48 << 20));               // 48   .. 52 MB (L0 pre-LN bf16)
  float* sbias_g = (float*)(ws + (52 << 20));               // 52   .. 52.25 MB [2][16][2048]

  k_packem<<<128 + NB * NS / 4 + 256, 256, 0, stream>>>(x, td, mask, tp, ee, te, hb,
                                                        Wq, Wk, Wv, Wo, bq, bk, bv,
                                                        wqkvT, woT, bqkv, sbias_g);

  for (int l = 0; l < NL; ++l) {
    const short* wqkvTl = wqkvT + (size_t)l * 768 * 256;
    const short* wvTl = wqkvTl + 512 * 256;
    const short* woTl = woT + (size_t)l * 65536;
    const float* bqkvl = bqkv + (size_t)l * 768;
    const float* bvl = bqkvl + 512;
    const float* bol = bo + (size_t)l * ND;
    const float* lngl = lng + (size_t)l * ND;
    const float* lnbl = lnb + (size_t)l * ND;
    const float* sbl = sbias_g + (size_t)l * 16 * NS;
    const bool last = (l == NL - 1);

    if (!last) {
      // Q+K -> qkv cols 0..511; V -> vT directly (transposed epilogue)
      k_gemm<1><<<dim3(M / 64, 4), 256, 0, stream>>>(hb, wqkvTl, bqkvl, qkv, 768, 1, 0, 0);
      k_gemmv<<<dim3(M / 64, 2), 256, 0, stream>>>(hb, wvTl, bvl, vT, 1, 0);
      k_attn<<<dim3(16 * 2, NH, NB), 256, 0, stream>>>(qkv, vT, sbl,
                                                       partO, partML, 0, NS, 2);
      k_pmerge<<<dim3(M / 64, 2), 256, 0, stream>>>(partO, partML, woTl, bol, hraw);
      k_lnb<<<dim3(NS / 4, NB), 256, 0, stream>>>(hraw, hb, lngl, lnbl);
    } else {
      // K all rows; V all rows -> vT; Q last-64 rows only
      k_gemm<1><<<dim3(M / 64, 2), 256, 0, stream>>>(hb, wqkvTl, bqkvl, qkv, 768, 1, 0, 256);
      k_gemmv<<<dim3(M / 64, 2), 256, 0, stream>>>(hb, wvTl, bvl, vT, 1, 0);
      k_gemm<1><<<dim3(NB, 2), 256, 0, stream>>>(hb, wqkvTl, bqkvl, qkv, 768, 32, 31, 0);
      k_attn<<<dim3(16, NH, NB), 256, 0, stream>>>(qkv, vT, sbl,
                                                   partO, partML, NS - 128, 128, 16);
      k_gmerge<<<dim3(NB, 2), 256, 0, stream>>>(partO, partML, woTl, bol, h);
      k_lnhead<<<NB, 256, 0, stream>>>(h, lngl, lnbl, Wc1, bc1, Wc2, bc2, out);
    }
  }
}

// Round 24
// 116.937 us; speedup vs baseline: 1.0189x; 1.0189x over previous
//
#include <hip/hip_runtime.h>
#include <math.h>

namespace {

constexpr int NB = 4, NS = 2048, ND = 256, NH = 4, NDK = 64, NL = 2, NT = 1000;
constexpr float L2E = 1.44269504089f;       // log2(e)
constexpr float QSCALE = 0.125f * L2E;      // 1/sqrt(DK) * log2(e), folded into Wq/bq

typedef short bfx8 __attribute__((ext_vector_type(8)));
typedef float f32x4 __attribute__((ext_vector_type(4)));
typedef float f32x16 __attribute__((ext_vector_type(16)));

static __device__ __forceinline__ short f2bf(float f) {
  union { float f; unsigned u; } v; v.f = f;
  unsigned u = v.u;
  unsigned r = (u + 0x7fffu + ((u >> 16) & 1u)) >> 16;   // RNE
  return (short)r;
}
static __device__ __forceinline__ float bf2f(short s) {
  union { float f; unsigned u; } v; v.u = ((unsigned)(unsigned short)s) << 16;
  return v.f;
}
static __device__ __forceinline__ float exp2_hw(float x) {
  float r;
  asm("v_exp_f32 %0, %1" : "=v"(r) : "v"(x));
  return r;
}
static __device__ __forceinline__ unsigned cvt_pk_bf16(float lo, float hi) {
  unsigned d;
  asm("v_cvt_pk_bf16_f32 %0, %1, %2" : "=v"(d) : "v"(lo), "v"(hi));
  return d;
}

// ---------------- fused weight-pack + embedding (one launch) -----------------
__global__ __launch_bounds__(256) void k_packem(const int* __restrict__ x,
                                                const int* __restrict__ td,
                                                const float* __restrict__ ee,
                                                const float* __restrict__ te,
                                                short* __restrict__ hb,
                                                const float* __restrict__ Wq,
                                                const float* __restrict__ Wk,
                                                const float* __restrict__ Wv,
                                                const float* __restrict__ Wo,
                                                const float* __restrict__ bq,
                                                const float* __restrict__ bk,
                                                const float* __restrict__ bv,
                                                short* __restrict__ wqkvT,
                                                short* __restrict__ woT,
                                                float* __restrict__ bqkv) {
  if (blockIdx.x < 128) {
    __shared__ float t[64][65];
    int bi = blockIdx.x;
    int z = bi >> 4, l = z >> 2, mat = z & 3;
    const float* src;
    short* dst;
    float scale = 1.f;
    if (mat == 0)      { src = Wq + (size_t)l * 65536; dst = wqkvT + (size_t)l * 768 * 256; scale = QSCALE; }
    else if (mat == 1) { src = Wk + (size_t)l * 65536; dst = wqkvT + (size_t)l * 768 * 256 + 256 * 256; }
    else if (mat == 2) { src = Wv + (size_t)l * 65536; dst = wqkvT + (size_t)l * 768 * 256 + 512 * 256; }
    else               { src = Wo + (size_t)l * 65536; dst = woT + (size_t)l * 65536; }
    int k0 = (bi & 3) * 64, n0 = ((bi >> 2) & 3) * 64;
    int c = threadIdx.x & 63, r4 = threadIdx.x >> 6;
    #pragma unroll
    for (int rr = 0; rr < 64; rr += 4) t[rr + r4][c] = src[(size_t)(k0 + rr + r4) * 256 + n0 + c];
    __syncthreads();
    #pragma unroll
    for (int rr = 0; rr < 64; rr += 4) {
      int n = rr + r4;
      dst[(size_t)(n0 + n) * 256 + k0 + c] = f2bf(t[c][n] * scale);
    }
    if (mat == 0 && (bi & 15) == 0) {
      for (int cc = threadIdx.x; cc < 768; cc += 256) {
        float v = cc < 256 ? bq[l * 256 + cc] * QSCALE
                           : (cc < 512 ? bk[l * 256 + cc - 256] : bv[l * 256 + cc - 512]);
        bqkv[l * 768 + cc] = v;
      }
    }
  } else {
    int lane = threadIdx.x & 63, r4 = threadIdx.x >> 6;
    int row = (blockIdx.x - 128) * 4 + r4;
    int xi = x[row];
    int tb = td[row];
    tb = tb < 0 ? 0 : (tb >= NT ? NT - 1 : tb);
    float4 e = ((const float4*)&ee[(size_t)xi * ND])[lane];
    float4 tv = ((const float4*)&te[(size_t)tb * ND])[lane];
    short4 ob;
    ob.x = f2bf(e.x + tv.x); ob.y = f2bf(e.y + tv.y);
    ob.z = f2bf(e.z + tv.z); ob.w = f2bf(e.w + tv.w);
    ((short4*)&hb[(size_t)row * ND])[lane] = ob;
  }
}

// ---------------- MFMA GEMM: 64x128 tile, BK=64, K=256 -----------------------
template <int OUT_BF16>
__global__ __launch_bounds__(256) void k_gemm(const short* __restrict__ A,
                                              const short* __restrict__ BT,
                                              const float* __restrict__ bias,
                                              void* __restrict__ C, int ldc,
                                              int mb_mul, int mb_add, int n_base) {
  constexpr int LP = 76;
  __shared__ short at[64][LP];
  __shared__ short bt[128][LP];
  int tid = threadIdx.x;
  int w = tid >> 6, lane = tid & 63, ln15 = lane & 15, g = lane >> 4;
  int m0 = (blockIdx.x * mb_mul + mb_add) * 64;
  int n0 = n_base + blockIdx.y * 128;
  int srow = tid >> 2, scol = (tid & 3) * 16;
  int brow = tid >> 1, bcol = (tid & 1) * 32;

  f32x4 acc[8];
  #pragma unroll
  for (int nt = 0; nt < 8; ++nt) acc[nt] = (f32x4){0.f, 0.f, 0.f, 0.f};

  bfx8 a0, a1, b0, b1, b2, b3;
  auto LOAD = [&](int kk0) {
    const short* as = &A[(size_t)(m0 + srow) * 256 + kk0 + scol];
    a0 = *(const bfx8*)as; a1 = *(const bfx8*)(as + 8);
    const short* bs = &BT[(size_t)(n0 + brow) * 256 + kk0 + bcol];
    b0 = *(const bfx8*)bs; b1 = *(const bfx8*)(bs + 8);
    b2 = *(const bfx8*)(bs + 16); b3 = *(const bfx8*)(bs + 24);
  };
  LOAD(0);
  for (int kk0 = 0; kk0 < 256; kk0 += 64) {
    __syncthreads();
    *(bfx8*)&at[srow][scol] = a0; *(bfx8*)&at[srow][scol + 8] = a1;
    *(bfx8*)&bt[brow][bcol] = b0; *(bfx8*)&bt[brow][bcol + 8] = b1;
    *(bfx8*)&bt[brow][bcol + 16] = b2; *(bfx8*)&bt[brow][bcol + 24] = b3;
    __syncthreads();
    if (kk0 + 64 < 256) LOAD(kk0 + 64);
    #pragma unroll
    for (int ks = 0; ks < 2; ++ks) {
      bfx8 af = *(const bfx8*)&at[w * 16 + ln15][ks * 32 + g * 8];
      #pragma unroll
      for (int nt = 0; nt < 8; ++nt) {
        bfx8 bf = *(const bfx8*)&bt[nt * 16 + ln15][ks * 32 + g * 8];
        acc[nt] = __builtin_amdgcn_mfma_f32_16x16x32_bf16(af, bf, acc[nt], 0, 0, 0);
      }
    }
  }

  #pragma unroll
  for (int nt = 0; nt < 8; ++nt) {
    int col = n0 + nt * 16 + ln15;
    float bb = bias[col];
    #pragma unroll
    for (int r = 0; r < 4; ++r) {
      int row = m0 + w * 16 + g * 4 + r;
      float val = acc[nt][r] + bb;
      if (OUT_BF16) ((short*)C)[(size_t)row * ldc + col] = f2bf(val);
      else          ((float*)C)[(size_t)row * ldc + col] = val;
    }
  }
}

// ---------------- fused merge+proj, layer 0 (NC=2, bf16 out) -----------------
__global__ __launch_bounds__(256) void k_pmerge(const short* __restrict__ partO,
                                                const float* __restrict__ partML,
                                                const short* __restrict__ BT,
                                                const float* __restrict__ bias,
                                                short* __restrict__ C) {
  constexpr int LP = 76;
  constexpr int NC = 2;
  __shared__ short at[64][LP];
  __shared__ short bt[128][LP];
  int tid = threadIdx.x;
  int w = tid >> 6, lane = tid & 63, ln15 = lane & 15, g = lane >> 4;
  int m0 = blockIdx.x * 64;
  int n0 = blockIdx.y * 128;
  int srow = tid >> 2, scol = (tid & 3) * 16;
  int brow = tid >> 1, bcol = (tid & 1) * 32;

  int grow = m0 + srow;
  int b = grow >> 11, s = grow & 2047;     // NS = 2048

  f32x4 acc[8];
  #pragma unroll
  for (int nt = 0; nt < 8; ++nt) acc[nt] = (f32x4){0.f, 0.f, 0.f, 0.f};

  bfx8 a0, a1, b0_, b1_, b2_, b3_;
  auto LOAD = [&](int kk0) {
    int hh2 = kk0 >> 6;
    size_t rbase = (size_t)(b * NH + hh2) * NS + s;
    float2 ml[NC];
    float M = -1e30f;
    #pragma unroll
    for (int c = 0; c < NC; ++c) {
      ml[c] = *(const float2*)&partML[(rbase + (size_t)c * 16 * NS) * 2];
      M = fmaxf(M, ml[c].x);
    }
    float wgt[NC], L = 0.f;
    #pragma unroll
    for (int c = 0; c < NC; ++c) { wgt[c] = exp2_hw(ml[c].x - M); L += ml[c].y * wgt[c]; }
    float inv = 1.f / L;
    float av[16];
    #pragma unroll
    for (int i = 0; i < 16; ++i) av[i] = 0.f;
    #pragma unroll
    for (int c = 0; c < NC; ++c) {
      float wc = wgt[c] * inv;
      size_t row = rbase + (size_t)c * 16 * NS;
      union { int4 v; short sh[8]; } ua, ub;
      ua.v = *(const int4*)&partO[row * 64 + scol];
      ub.v = *(const int4*)&partO[row * 64 + scol + 8];
      #pragma unroll
      for (int i = 0; i < 8; ++i) {
        av[i]     = fmaf(bf2f(ua.sh[i]), wc, av[i]);
        av[8 + i] = fmaf(bf2f(ub.sh[i]), wc, av[8 + i]);
      }
    }
    union { bfx8 v; short sh[8]; } pa, pb;
    #pragma unroll
    for (int i = 0; i < 8; ++i) { pa.sh[i] = f2bf(av[i]); pb.sh[i] = f2bf(av[8 + i]); }
    a0 = pa.v; a1 = pb.v;
    const short* bs = &BT[(size_t)(n0 + brow) * 256 + kk0 + bcol];
    b0_ = *(const bfx8*)bs; b1_ = *(const bfx8*)(bs + 8);
    b2_ = *(const bfx8*)(bs + 16); b3_ = *(const bfx8*)(bs + 24);
  };
  LOAD(0);
  for (int kk0 = 0; kk0 < 256; kk0 += 64) {
    __syncthreads();
    *(bfx8*)&at[srow][scol] = a0; *(bfx8*)&at[srow][scol + 8] = a1;
    *(bfx8*)&bt[brow][bcol] = b0_; *(bfx8*)&bt[brow][bcol + 8] = b1_;
    *(bfx8*)&bt[brow][bcol + 16] = b2_; *(bfx8*)&bt[brow][bcol + 24] = b3_;
    __syncthreads();
    if (kk0 + 64 < 256) LOAD(kk0 + 64);
    #pragma unroll
    for (int ks = 0; ks < 2; ++ks) {
      bfx8 af = *(const bfx8*)&at[w * 16 + ln15][ks * 32 + g * 8];
      #pragma unroll
      for (int nt = 0; nt < 8; ++nt) {
        bfx8 bf = *(const bfx8*)&bt[nt * 16 + ln15][ks * 32 + g * 8];
        acc[nt] = __builtin_amdgcn_mfma_f32_16x16x32_bf16(af, bf, acc[nt], 0, 0, 0);
      }
    }
  }

  #pragma unroll
  for (int nt = 0; nt < 8; ++nt) {
    int col = n0 + nt * 16 + ln15;
    float bb = bias[col];
    #pragma unroll
    for (int r = 0; r < 4; ++r) {
      int row = m0 + w * 16 + g * 4 + r;
      C[(size_t)row * 256 + col] = f2bf(acc[nt][r] + bb);
    }
  }
}

// ---------------- fused merge+proj, layer-1 tail (NC=16, fp32 out) -----------
__global__ __launch_bounds__(256) void k_gmerge(const short* __restrict__ partO,
                                                const float* __restrict__ partML,
                                                const short* __restrict__ BT,
                                                const float* __restrict__ bias,
                                                float* __restrict__ C) {
  constexpr int LP = 76;
  constexpr int NC = 16;
  __shared__ short at[64][LP];
  __shared__ short bt[128][LP];
  int tid = threadIdx.x;
  int w = tid >> 6, lane = tid & 63, ln15 = lane & 15, g = lane >> 4;
  int m0 = (blockIdx.x * 32 + 31) * 64;    // last 64 rows of batch blockIdx.x
  int n0 = blockIdx.y * 128;
  int srow = tid >> 2, scol = (tid & 3) * 16;
  int brow = tid >> 1, bcol = (tid & 1) * 32;

  int grow = m0 + srow;
  int b = grow >> 11, s = grow & 2047;
  int qloc = s - (NS - 128);               // 64..127 within the 128-q partial block

  f32x4 acc[8];
  #pragma unroll
  for (int nt = 0; nt < 8; ++nt) acc[nt] = (f32x4){0.f, 0.f, 0.f, 0.f};

  bfx8 a0, a1, b0_, b1_, b2_, b3_;
  auto LOAD = [&](int kk0) {
    int hh2 = kk0 >> 6;
    size_t rbase = (size_t)(b * NH + hh2) * 128 + qloc;
    float M = -1e30f;
    float mls[NC], lls[NC];
    #pragma unroll
    for (int c = 0; c < NC; ++c) {
      float2 ml = *(const float2*)&partML[(rbase + (size_t)c * 16 * 128) * 2];
      mls[c] = ml.x; lls[c] = ml.y;
      M = fmaxf(M, ml.x);
    }
    float L = 0.f, wgt[NC];
    #pragma unroll
    for (int c = 0; c < NC; ++c) { wgt[c] = exp2_hw(mls[c] - M); L += lls[c] * wgt[c]; }
    float inv = 1.f / L;
    float av[16];
    #pragma unroll
    for (int i = 0; i < 16; ++i) av[i] = 0.f;
    #pragma unroll
    for (int c = 0; c < NC; ++c) {
      float wc = wgt[c] * inv;
      size_t row = rbase + (size_t)c * 16 * 128;
      union { int4 v; short sh[8]; } ua, ub;
      ua.v = *(const int4*)&partO[row * 64 + scol];
      ub.v = *(const int4*)&partO[row * 64 + scol + 8];
      #pragma unroll
      for (int i = 0; i < 8; ++i) {
        av[i]     = fmaf(bf2f(ua.sh[i]), wc, av[i]);
        av[8 + i] = fmaf(bf2f(ub.sh[i]), wc, av[8 + i]);
      }
    }
    union { bfx8 v; short sh[8]; } pa, pb;
    #pragma unroll
    for (int i = 0; i < 8; ++i) { pa.sh[i] = f2bf(av[i]); pb.sh[i] = f2bf(av[8 + i]); }
    a0 = pa.v; a1 = pb.v;
    const short* bs = &BT[(size_t)(n0 + brow) * 256 + kk0 + bcol];
    b0_ = *(const bfx8*)bs; b1_ = *(const bfx8*)(bs + 8);
    b2_ = *(const bfx8*)(bs + 16); b3_ = *(const bfx8*)(bs + 24);
  };
  LOAD(0);
  for (int kk0 = 0; kk0 < 256; kk0 += 64) {
    __syncthreads();
    *(bfx8*)&at[srow][scol] = a0; *(bfx8*)&at[srow][scol + 8] = a1;
    *(bfx8*)&bt[brow][bcol] = b0_; *(bfx8*)&bt[brow][bcol + 8] = b1_;
    *(bfx8*)&bt[brow][bcol + 16] = b2_; *(bfx8*)&bt[brow][bcol + 24] = b3_;
    __syncthreads();
    if (kk0 + 64 < 256) LOAD(kk0 + 64);
    #pragma unroll
    for (int ks = 0; ks < 2; ++ks) {
      bfx8 af = *(const bfx8*)&at[w * 16 + ln15][ks * 32 + g * 8];
      #pragma unroll
      for (int nt = 0; nt < 8; ++nt) {
        bfx8 bf = *(const bfx8*)&bt[nt * 16 + ln15][ks * 32 + g * 8];
        acc[nt] = __builtin_amdgcn_mfma_f32_16x16x32_bf16(af, bf, acc[nt], 0, 0, 0);
      }
    }
  }

  #pragma unroll
  for (int nt = 0; nt < 8; ++nt) {
    int col = n0 + nt * 16 + ln15;
    float bb = bias[col];
    #pragma unroll
    for (int r = 0; r < 4; ++r) {
      int row = m0 + w * 16 + g * 4 + r;
      C[(size_t)row * 256 + col] = acc[nt][r] + bb;
    }
  }
}

// ---------------- V^T + bias prepass: plain [dim][key] transpose -------------
__global__ __launch_bounds__(256) void k_frag(const short* __restrict__ qkv,
                                              const int* __restrict__ td,
                                              const int* __restrict__ mask,
                                              const float* __restrict__ tp,
                                              short* __restrict__ vT,
                                              float* __restrict__ sbias_g) {
  __shared__ short vl[64][72];
  int tile = blockIdx.x, hh = blockIdx.y, b = blockIdx.z;
  int t = threadIdx.x;
  int k0 = tile * 64;
  {
    int key = t >> 2, dg = (t & 3) * 16;
    const short* vsrc = &qkv[(size_t)(b * NS + k0 + key) * 768 + 512 + hh * NDK + dg];
    bfx8 v0 = *(const bfx8*)vsrc, v1 = *(const bfx8*)(vsrc + 8);
    *(bfx8*)&vl[key][dg] = v0;
    *(bfx8*)&vl[key][dg + 8] = v1;
  }
  if (t < 64) {
    int kk = k0 + t;
    int tb = td[b * NS + kk];
    tb = tb < 0 ? 0 : (tb >= NT ? NT - 1 : tb);
    sbias_g[(size_t)(b * NH + hh) * NS + kk] = mask[b * NS + kk] ? tp[tb * NH + hh] * L2E : -1e9f;
  }
  __syncthreads();
  int dim = t >> 2, c0 = (t & 3) * 16;
  short outv[16];
  #pragma unroll
  for (int j = 0; j < 16; ++j) outv[j] = vl[c0 + j][dim];
  short* dst = &vT[(((size_t)(b * NH + hh) * 32 + tile) * 64 + dim) * 64 + c0];
  *(int4*)dst = *(const int4*)outv;
  *(int4*)(dst + 8) = *(const int4*)(outv + 8);
}

// ---------------- MFMA flash attention: 32x32x16 fragments (R20 proven) ------
__global__ __launch_bounds__(256) void k_attn(const short* __restrict__ qkv,
                                              const short* __restrict__ vT,
                                              const float* __restrict__ sbias_g,
                                              short* __restrict__ partO,
                                              float* __restrict__ partML,
                                              int q_base, int qcount, int nchunk) {
  constexpr int LP = 76;
  __shared__ short kt[64][LP];   // K tile [key][dim]
  __shared__ short vt[64][LP];   // V^T tile [dim][key]
  __shared__ float sbias[64];

  int tid = threadIdx.x;
  int w = tid >> 6, lane = tid & 63, q31 = lane & 31, hl = lane >> 5;
  int b = blockIdx.z, hh = blockIdx.y;
  int bh = b * NH + hh;
  int qtile = blockIdx.x / nchunk;
  int chunk = blockIdx.x - qtile * nchunk;
  int niter = NS / (64 * nchunk);
  int tbase = chunk * niter;
  int q0 = q_base + qtile * 128;
  int qq = q0 + w * 32 + q31;      // this lane's query row

  bfx8 aq[4];
  #pragma unroll
  for (int ki = 0; ki < 4; ++ki)
    aq[ki] = *(const bfx8*)&qkv[(size_t)(b * NS + qq) * 768 + hh * NDK + ki * 16 + hl * 8];

  f32x16 o[2];
  #pragma unroll
  for (int dt = 0; dt < 2; ++dt)
    #pragma unroll
    for (int i = 0; i < 16; ++i) o[dt][i] = 0.f;
  float m = -1e30f, lsum = 0.f;

  int srow = tid >> 2, scg = (tid & 3) * 16;

  bfx8 kr0, kr1, vr0, vr1;
  float br = 0.f;
  auto loadset = [&](int it) {
    int tt = tbase + it;
    int k0 = tt * 64;
    const short* ksrc = &qkv[(size_t)(b * NS + k0 + srow) * 768 + 256 + hh * NDK + scg];
    kr0 = *(const bfx8*)ksrc; kr1 = *(const bfx8*)(ksrc + 8);
    const short* vsrc = &vT[(((size_t)bh * 32 + tt) * 64 + srow) * 64 + scg];
    vr0 = *(const bfx8*)vsrc; vr1 = *(const bfx8*)(vsrc + 8);
    if (tid < 64) br = sbias_g[(size_t)bh * NS + k0 + tid];
  };

  loadset(0);
  for (int it = 0; it < niter; ++it) {
    __syncthreads();
    *(bfx8*)&kt[srow][scg] = kr0;
    *(bfx8*)&kt[srow][scg + 8] = kr1;
    *(bfx8*)&vt[srow][scg] = vr0;
    *(bfx8*)&vt[srow][scg + 8] = vr1;
    if (tid < 64) sbias[tid] = br;
    __syncthreads();
    if (it + 1 < niter) loadset(it + 1);

    f32x16 c[2];
    #pragma unroll
    for (int kt2 = 0; kt2 < 2; ++kt2)
      #pragma unroll
      for (int i = 0; i < 16; ++i) c[kt2][i] = 0.f;
    __builtin_amdgcn_s_setprio(1);
    #pragma unroll
    for (int kt2 = 0; kt2 < 2; ++kt2) {
      #pragma unroll
      for (int ki = 0; ki < 4; ++ki) {
        bfx8 kf = *(const bfx8*)&kt[kt2 * 32 + q31][ki * 16 + hl * 8];
        c[kt2] = __builtin_amdgcn_mfma_f32_32x32x16_bf16(kf, aq[ki], c[kt2], 0, 0, 0);
      }
    }
    __builtin_amdgcn_s_setprio(0);

    #pragma unroll
    for (int kt2 = 0; kt2 < 2; ++kt2) {
      #pragma unroll
      for (int rg = 0; rg < 4; ++rg) {
        float4 bb = *(const float4*)&sbias[kt2 * 32 + rg * 8 + hl * 4];
        c[kt2][rg * 4 + 0] += bb.x; c[kt2][rg * 4 + 1] += bb.y;
        c[kt2][rg * 4 + 2] += bb.z; c[kt2][rg * 4 + 3] += bb.w;
      }
    }
    float rm = c[0][0];
    #pragma unroll
    for (int kt2 = 0; kt2 < 2; ++kt2)
      #pragma unroll
      for (int i = 0; i < 16; ++i) rm = fmaxf(rm, c[kt2][i]);
    rm = fmaxf(rm, __shfl_xor(rm, 32, 64));
    if (__any(rm > m + 10.f)) {
      float nm = fmaxf(m, rm);
      float scl = exp2_hw(m - nm);
      m = nm;
      lsum *= scl;
      #pragma unroll
      for (int dt = 0; dt < 2; ++dt)
        #pragma unroll
        for (int i = 0; i < 16; ++i) o[dt][i] *= scl;
    }
    float ts = 0.f;
    #pragma unroll
    for (int kt2 = 0; kt2 < 2; ++kt2)
      #pragma unroll
      for (int i = 0; i < 16; ++i) { c[kt2][i] = exp2_hw(c[kt2][i] - m); ts += c[kt2][i]; }
    lsum += ts;

    __builtin_amdgcn_s_setprio(1);
    #pragma unroll
    for (int kt2 = 0; kt2 < 2; ++kt2) {
      #pragma unroll
      for (int ks = 0; ks < 2; ++ks) {
        unsigned pa0 = cvt_pk_bf16(c[kt2][8 * ks + 0], c[kt2][8 * ks + 1]);
        unsigned pa1 = cvt_pk_bf16(c[kt2][8 * ks + 2], c[kt2][8 * ks + 3]);
        unsigned pb0 = cvt_pk_bf16(c[kt2][8 * ks + 4], c[kt2][8 * ks + 5]);
        unsigned pb1 = cvt_pk_bf16(c[kt2][8 * ks + 6], c[kt2][8 * ks + 7]);
        asm volatile("v_permlane32_swap_b32 %0, %1" : "+v"(pa0), "+v"(pb0));
        asm volatile("v_permlane32_swap_b32 %0, %1" : "+v"(pa1), "+v"(pb1));
        union { unsigned u[4]; bfx8 v; } pf;
        pf.u[0] = pa0; pf.u[1] = pa1; pf.u[2] = pb0; pf.u[3] = pb1;
        #pragma unroll
        for (int dt = 0; dt < 2; ++dt) {
          bfx8 vf = *(const bfx8*)&vt[dt * 32 + q31][kt2 * 32 + ks * 16 + hl * 8];
          o[dt] = __builtin_amdgcn_mfma_f32_32x32x16_bf16(vf, pf.v, o[dt], 0, 0, 0);
        }
      }
    }
    __builtin_amdgcn_s_setprio(0);
  }

  lsum += __shfl_xor(lsum, 32, 64);

  size_t rowi = (size_t)(chunk * 16 + bh) * qcount + qtile * 128 + w * 32 + q31;
  #pragma unroll
  for (int dt = 0; dt < 2; ++dt) {
    #pragma unroll
    for (int rg = 0; rg < 4; ++rg) {
      int2 pk;
      pk.x = (int)cvt_pk_bf16(o[dt][rg * 4 + 0], o[dt][rg * 4 + 1]);
      pk.y = (int)cvt_pk_bf16(o[dt][rg * 4 + 2], o[dt][rg * 4 + 3]);
      *(int2*)&partO[rowi * 64 + dt * 32 + rg * 8 + hl * 4] = pk;
    }
  }
  if (hl == 0) { partML[rowi * 2] = m; partML[rowi * 2 + 1] = lsum; }
}

// ---------------- layernorm bf16->bf16 (layer 0, full rows) ------------------
__global__ __launch_bounds__(256) void k_lnb(const short* __restrict__ in,
                                             short* __restrict__ hb,
                                             const float* __restrict__ g_,
                                             const float* __restrict__ b_) {
  int lane = threadIdx.x & 63, r4 = threadIdx.x >> 6;
  size_t row = (size_t)blockIdx.y * NS + blockIdx.x * 4 + r4;
  short4 sv = ((const short4*)&in[row * ND])[lane];
  float vx = bf2f(sv.x), vy = bf2f(sv.y), vz = bf2f(sv.z), vw = bf2f(sv.w);
  float s = vx + vy + vz + vw;
  #pragma unroll
  for (int off = 1; off < 64; off <<= 1) s += __shfl_xor(s, off, 64);
  float mu = s * (1.f / ND);
  float dx = vx - mu, dy = vy - mu, dz = vz - mu, dw = vw - mu;
  float q = dx * dx + dy * dy + dz * dz + dw * dw;
  #pragma unroll
  for (int off = 1; off < 64; off <<= 1) q += __shfl_xor(q, off, 64);
  float rr = rsqrtf(q * (1.f / ND) + 1e-5f);
  float4 gg = ((const float4*)g_)[lane];
  float4 bb = ((const float4*)b_)[lane];
  short4 ob;
  ob.x = f2bf(dx * rr * gg.x + bb.x);
  ob.y = f2bf(dy * rr * gg.y + bb.y);
  ob.z = f2bf(dz * rr * gg.z + bb.z);
  ob.w = f2bf(dw * rr * gg.w + bb.w);
  ((short4*)&hb[row * ND])[lane] = ob;
}

// ---------------- fused tail LN (row NS-1 only) + classifier head ------------
__global__ __launch_bounds__(256) void k_lnhead(const float* __restrict__ h,
                                                const float* __restrict__ g_,
                                                const float* __restrict__ b_,
                                                const float* __restrict__ Wc1,
                                                const float* __restrict__ bc1,
                                                const float* __restrict__ Wc2,
                                                const float* __restrict__ bc2,
                                                float* __restrict__ out) {
  __shared__ float rowv[256];
  __shared__ float red[256];
  int b = blockIdx.x, j = threadIdx.x;
  float v = h[(size_t)(b * NS + NS - 1) * ND + j];
  red[j] = v;
  __syncthreads();
  for (int off = 128; off > 0; off >>= 1) {
    if (j < off) red[j] += red[j + off];
    __syncthreads();
  }
  float mu = red[0] * (1.f / ND);
  __syncthreads();
  float d = v - mu;
  red[j] = d * d;
  __syncthreads();
  for (int off = 128; off > 0; off >>= 1) {
    if (j < off) red[j] += red[j + off];
    __syncthreads();
  }
  float rr = rsqrtf(red[0] * (1.f / ND) + 1e-5f);
  rowv[j] = d * rr * g_[j] + b_[j];
  __syncthreads();
  float hid = 0.f;
  if (j < 128) {
    hid = bc1[j];
    for (int dd = 0; dd < ND; ++dd) hid = fmaf(rowv[dd], Wc1[dd * 128 + j], hid);
    hid = fmaxf(hid, 0.f) * Wc2[j];
  }
  __syncthreads();
  red[j] = j < 128 ? hid : 0.f;
  __syncthreads();
  for (int off = 64; off > 0; off >>= 1) {
    if (j < off) red[j] += red[j + off];
    __syncthreads();
  }
  if (j == 0) out[b] = 1.f / (1.f + __expf(-(red[0] + bc2[0])));
}

}  // namespace

extern "C" void kernel_launch(void* const* d_in, const int* in_sizes, int n_in,
                              void* d_out, int out_size, void* d_ws, size_t ws_size,
                              hipStream_t stream) {
  const int* x = (const int*)d_in[0];
  const int* td = (const int*)d_in[1];
  const int* mask = (const int*)d_in[2];
  const float* ee = (const float*)d_in[3];
  const float* te = (const float*)d_in[4];
  const float* Wq = (const float*)d_in[5];
  const float* bq = (const float*)d_in[6];
  const float* Wk = (const float*)d_in[7];
  const float* bk = (const float*)d_in[8];
  const float* Wv = (const float*)d_in[9];
  const float* bv = (const float*)d_in[10];
  const float* tp = (const float*)d_in[11];
  const float* Wo = (const float*)d_in[12];
  const float* bo = (const float*)d_in[13];
  const float* lng = (const float*)d_in[14];
  const float* lnb = (const float*)d_in[15];
  const float* Wc1 = (const float*)d_in[16];
  const float* bc1 = (const float*)d_in[17];
  const float* Wc2 = (const float*)d_in[18];
  const float* bc2 = (const float*)d_in[19];
  float* out = (float*)d_out;

  char* ws = (char*)d_ws;
  const size_t M = (size_t)NB * NS;  // 8192
  // Disjoint layout (verified R17/R20-R22)
  short* qkv     = (short*)(ws);                            // 0    .. 12 MB
  float* h       = (float*)(ws + (12 << 20));               // 12   .. 20 MB (L1 tail rows)
  short* hb      = (short*)(ws + (20 << 20));               // 20   .. 24 MB
  short* vT      = (short*)(ws + (24 << 20));               // 24   .. 28 MB
  float* sbias_g = (float*)(ws + (28 << 20));               // 28   .. 28.125 MB
  short* wqkvT   = (short*)(ws + (28 << 20) + (128 << 10)); // 28.125 .. 28.875 MB
  short* woT     = (short*)(ws + (28 << 20) + (896 << 10)); // 28.875 .. 29.125 MB
  float* bqkv    = (float*)(ws + (28 << 20) + (1152 << 10)); // 29.125 .. 29.133 MB
  short* partO   = (short*)(ws + (30 << 20));               // 30   .. 46.8 MB
  float* partML  = (float*)(ws + (47 << 20));               // 47   .. 48 MB
  short* hraw    = (short*)(ws + (48 << 20));               // 48   .. 52 MB (L0 pre-LN bf16)

  k_packem<<<128 + NB * NS / 4, 256, 0, stream>>>(x, td, ee, te, hb,
                                                  Wq, Wk, Wv, Wo, bq, bk, bv,
                                                  wqkvT, woT, bqkv);

  for (int l = 0; l < NL; ++l) {
    const short* wqkvTl = wqkvT + (size_t)l * 768 * 256;
    const short* woTl = woT + (size_t)l * 65536;
    const float* bqkvl = bqkv + (size_t)l * 768;
    const float* bol = bo + (size_t)l * ND;
    const float* tpl = tp + (size_t)l * NT * NH;
    const float* lngl = lng + (size_t)l * ND;
    const float* lnbl = lnb + (size_t)l * ND;
    const bool last = (l == NL - 1);

    if (!last) {
      k_gemm<1><<<dim3(M / 64, 6), 256, 0, stream>>>(hb, wqkvTl, bqkvl, qkv, 768, 1, 0, 0);
    } else {
      k_gemm<1><<<dim3(M / 64, 4), 256, 0, stream>>>(hb, wqkvTl, bqkvl, qkv, 768, 1, 0, 256);
      k_gemm<1><<<dim3(NB, 2), 256, 0, stream>>>(hb, wqkvTl, bqkvl, qkv, 768, 32, 31, 0);
    }

    k_frag<<<dim3(32, NH, NB), 256, 0, stream>>>(qkv, td, mask, tpl, vT, sbias_g);

    if (!last) {
      k_attn<<<dim3(16 * 2, NH, NB), 256, 0, stream>>>(qkv, vT, sbias_g,
                                                       partO, partML, 0, NS, 2);
      k_pmerge<<<dim3(M / 64, 2), 256, 0, stream>>>(partO, partML, woTl, bol, hraw);
      k_lnb<<<dim3(NS / 4, NB), 256, 0, stream>>>(hraw, hb, lngl, lnbl);
    } else {
      k_attn<<<dim3(16, NH, NB), 256, 0, stream>>>(qkv, vT, sbias_g,
                                                   partO, partML, NS - 128, 128, 16);
      k_gmerge<<<dim3(NB, 2), 256, 0, stream>>>(partO, partML, woTl, bol, h);
      k_lnhead<<<NB, 256, 0, stream>>>(h, lngl, lnbl, Wc1, bc1, Wc2, bc2, out);
    }
  }
}